// Round 13
// baseline (59.267 us; speedup 1.0000x reference)
//
#include <hip/hip_runtime.h>
#include <hip/hip_bf16.h>
#include <math.h>

#define NLOOP 8
#define BB 8
#define LLEN 2048
#define DD 768
#define VV 50288
#define HALT 50277
#define EPSF 1e-5f

#define BN 64
#define BKK 32
#define KSTEPS (DD / BKK)              // 24
#define NBLK ((VV + BN - 1) / BN)      // 786
#define DAHEAD 3                       // DMA issue-ahead (steps)
#define NBUF 4                         // LDS ring buffers (>= DAHEAD+1)

typedef short bf16x8 __attribute__((ext_vector_type(8)));
typedef float f32x4 __attribute__((ext_vector_type(4)));

__device__ __forceinline__ unsigned short f32_to_bf16(float f) {
    unsigned u = __builtin_bit_cast(unsigned, f);
    unsigned r = (u + 0x7FFFu + ((u >> 16) & 1u)) >> 16;
    return (unsigned short)r;
}

// ---------------- Kernel 1: gather + RMSNorm + target logits ----------------
__global__ __launch_bounds__(256) void k_prep(
    const float* __restrict__ x, const float* __restrict__ res,
    const float* __restrict__ nw, const float* __restrict__ W,
    const int* __restrict__ ans_starts, const int* __restrict__ chain_targets,
    const int* __restrict__ chain_lens,
    unsigned short* __restrict__ hbf, float* __restrict__ tgt_logit,
    unsigned int* __restrict__ counter)
{
    if (blockIdx.x == 0 && threadIdx.x == 0) *counter = 0u;   // for k_combine

    int lb = blockIdx.x, l = lb >> 3, b = lb & 7;
    int tid = threadIdx.x, lane = tid & 63, wave = tid >> 6;
    int as = ans_starts[b];
    int pos = as - 1;
    pos = pos < 0 ? 0 : (pos > LLEN - 1 ? LLEN - 1 : pos);
    size_t base = ((size_t)lb * LLEN + (size_t)pos) * DD;

    float hv[3];
    float ss = 0.f;
#pragma unroll
    for (int i = 0; i < 3; ++i) {
        int d = tid + i * 256;
        float v = x[base + d] + res[base + d];
        hv[i] = v;
        ss += v * v;
    }
#pragma unroll
    for (int off = 32; off; off >>= 1) ss += __shfl_down(ss, off);
    __shared__ float red[4];
    __shared__ float bc;
    if (lane == 0) red[wave] = ss;
    __syncthreads();
    if (tid == 0) bc = red[0] + red[1] + red[2] + red[3];
    __syncthreads();
    float rs = rsqrtf(bc / (float)DD + EPSF);

    int cl = chain_lens[b];
    int tix = l < cl - 1 ? l : cl - 1;
    int tgt = chain_targets[b * NLOOP + tix];
    bool tok = (tgt >= 0) && (tgt < VV);

    float dp = 0.f;
#pragma unroll
    for (int i = 0; i < 3; ++i) {
        int d = tid + i * 256;
        float h = hv[i] * rs * nw[d];
        hbf[(size_t)lb * DD + d] = f32_to_bf16(h);
        if (tok) dp += h * W[(size_t)tgt * DD + d];
    }
#pragma unroll
    for (int off = 32; off; off >>= 1) dp += __shfl_down(dp, off);
    __syncthreads();
    if (lane == 0) red[wave] = dp;
    __syncthreads();
    if (tid == 0) tgt_logit[lb] = red[0] + red[1] + red[2] + red[3];
}

// ---------------- Kernel 2: DMA-staged (global_load_lds) MFMA logits --------
// B staged f32 via global_load_lds width=16: 4-buffer ring (32KB), issue-ahead
// 3 steps, counted vmcnt(4)+s_barrier per step (never-drain, T4). Per-lane
// pre-swizzled SOURCE (m173) with linear LDS dest: LDS slot c8 of row r holds
// source k-chunk c8^(r&6) -> read slot s=2q^(c&6) is 32B-aligned pair.
// f32->bf16 conversion on consume side via v_cvt_pk (__float22bfloat162_rn).
// Fragment values fed to MFMA identical to R12 -> output mapping unchanged.
// Partials written TRANSPOSED: pmax[row * NBLK + blk].
__global__ __launch_bounds__(256) void k_logits(
    const float* __restrict__ W, const unsigned short* __restrict__ hbf,
    float* __restrict__ pmax, float* __restrict__ psum, int* __restrict__ parg)
{
    __shared__ float Bs[NBUF][64 * 32];   // 4 x 8KB f32, rows of 128B

    int blk = blockIdx.x;
    int v0 = blk * BN;
    int tid = threadIdx.x;
    int wave = tid >> 6, lane = tid & 63, q = lane >> 4, c = lane & 15;

    // ---- A preload first (oldest in vm queue; L2-hot bf16 from prep) ----
    const unsigned short* Ap = hbf + (size_t)(16 * wave + c) * DD + q * 8;
    bf16x8 A[KSTEPS];
#pragma unroll
    for (int ks = 0; ks < KSTEPS; ++ks)
        A[ks] = *(const bf16x8*)(Ap + ks * BKK);

    // ---- per-lane DMA source setup: wave w stages local rows 16w..16w+15 ---
    int rl0 = wave * 16 + (lane >> 3);      // inst 0: local row
    int rl1 = rl0 + 8;                      // inst 1
    int g0 = v0 + rl0; if (g0 >= VV) g0 = 0;   // clamp; cols masked later
    int g1 = v0 + rl1; if (g1 >= VV) g1 = 0;
    int sw0 = (lane & 7) ^ (rl0 & 6);       // pre-swizzled source chunk
    int sw1 = (lane & 7) ^ (rl1 & 6);
    const float* p0 = W + (size_t)g0 * DD + sw0 * 4;
    const float* p1 = W + (size_t)g1 * DD + sw1 * 4;

    auto dma = [&](int ks, int buf) {
        __builtin_amdgcn_global_load_lds(
            (const __attribute__((address_space(1))) unsigned int*)(p0 + ks * BKK),
            (__attribute__((address_space(3))) unsigned int*)(&Bs[buf][wave * 512]), 16, 0, 0);
        __builtin_amdgcn_global_load_lds(
            (const __attribute__((address_space(1))) unsigned int*)(p1 + ks * BKK),
            (__attribute__((address_space(3))) unsigned int*)(&Bs[buf][wave * 512 + 256]), 16, 0, 0);
    };

    f32x4 acc[4];
#pragma unroll
    for (int n = 0; n < 4; ++n) acc[n] = (f32x4){0.f, 0.f, 0.f, 0.f};

    const int slot = ((2 * q) ^ (c & 6)) * 4;   // float offset of lo-half, uniform in n

    auto mfma_step = [&](int buf, int ks) {
#pragma unroll
        for (int n = 0; n < 4; ++n) {
            const float* bp = &Bs[buf][(c + 16 * n) * 32 + slot];
            f32x4 lo = *(const f32x4*)bp;
            f32x4 hi = *(const f32x4*)(bp + 4);
            union { bf16x8 v; __hip_bfloat162 h[4]; } u;
            u.h[0] = __float22bfloat162_rn(make_float2(lo[0], lo[1]));
            u.h[1] = __float22bfloat162_rn(make_float2(lo[2], lo[3]));
            u.h[2] = __float22bfloat162_rn(make_float2(hi[0], hi[1]));
            u.h[3] = __float22bfloat162_rn(make_float2(hi[2], hi[3]));
            acc[n] = __builtin_amdgcn_mfma_f32_16x16x32_bf16(A[ks], u.v, acc[n], 0, 0, 0);
        }
    };

    // ---- prologue: 3 steps in flight ----
    dma(0, 0); dma(1, 1); dma(2, 2);

#pragma unroll
    for (int ks = 0; ks < KSTEPS; ++ks) {       // fully unrolled: all idx static
        const int rem = (KSTEPS - 1 - ks) * 2;  // DMAs allowed to stay in flight
        if (rem >= 4)      { asm volatile("s_waitcnt vmcnt(4)\n\ts_barrier" ::: "memory"); }
        else if (rem == 2) { asm volatile("s_waitcnt vmcnt(2)\n\ts_barrier" ::: "memory"); }
        else               { asm volatile("s_waitcnt vmcnt(0)\n\ts_barrier" ::: "memory"); }
        if (ks + DAHEAD < KSTEPS) dma(ks + DAHEAD, (ks + DAHEAD) & (NBUF - 1));
        mfma_step(ks & (NBUF - 1), ks);
    }

    // ---- wave-internal per-row max / argmax / sumexp over 64 block cols ----
    const float NEGINF = -__builtin_inff();
#pragma unroll
    for (int r = 0; r < 4; ++r) {
        float val = NEGINF; int idx = 0x7fffffff;
#pragma unroll
        for (int n = 0; n < 4; ++n) {
            int colg = v0 + 16 * n + c;
            float v = (colg < VV) ? acc[n][r] : NEGINF;
            if (v > val || (v == val && colg < idx)) { val = v; idx = colg; }
        }
#pragma unroll
        for (int off = 1; off < 16; off <<= 1) {
            float ov = __shfl_xor(val, off);
            int oi = __shfl_xor(idx, off);
            if (ov > val || (ov == val && oi < idx)) { val = ov; idx = oi; }
        }
        float M = val;          // all 16 lanes of the q-group hold the row max
        float e = 0.f;
#pragma unroll
        for (int n = 0; n < 4; ++n) {
            int colg = v0 + 16 * n + c;
            e += (colg < VV) ? __expf(acc[n][r] - M) : 0.f;
        }
#pragma unroll
        for (int off = 1; off < 16; off <<= 1) e += __shfl_xor(e, off);
        if (c == 0) {
            int row = 16 * wave + 4 * q + r;
            pmax[(size_t)row * NBLK + blk] = M;
            psum[(size_t)row * NBLK + blk] = e;
            parg[(size_t)row * NBLK + blk] = idx;
        }
    }
}

// ------- Kernel 3: parallel combine + fused last-block scalar epilogue ------
__global__ __launch_bounds__(256) void k_combine(
    const float* __restrict__ pmax, const float* __restrict__ psum,
    const int* __restrict__ parg, const float* __restrict__ tgt_logit,
    const int* __restrict__ ans_starts, const int* __restrict__ chain_targets,
    const int* __restrict__ chain_lens,
    float* __restrict__ logZ, int* __restrict__ pred,
    unsigned int* __restrict__ counter, float* __restrict__ out)
{
    int r = blockIdx.x;                 // row 0..63
    int tid = threadIdx.x;
    int wave = tid >> 6, lane = tid & 63;
    const float NEGINF = -__builtin_inff();

    const float* pm = pmax + (size_t)r * NBLK;
    const float* ps = psum + (size_t)r * NBLK;
    const int*   pa = parg + (size_t)r * NBLK;

    float M = NEGINF; int A_ = 0x7fffffff;
    for (int i = tid; i < NBLK; i += 256) {
        float m = pm[i];
        int a = pa[i];
        if (m > M || (m == M && a < A_)) { M = m; A_ = a; }
    }
#pragma unroll
    for (int off = 1; off < 64; off <<= 1) {
        float ov = __shfl_xor(M, off);
        int oa = __shfl_xor(A_, off);
        if (ov > M || (ov == M && oa < A_)) { M = ov; A_ = oa; }
    }
    __shared__ float sm[4]; __shared__ int sa[4]; __shared__ float ssum[4];
    __shared__ int lastflag;
    if (lane == 0) { sm[wave] = M; sa[wave] = A_; }
    __syncthreads();
    if (tid == 0) {
#pragma unroll
        for (int w = 1; w < 4; ++w)
            if (sm[w] > sm[0] || (sm[w] == sm[0] && sa[w] < sa[0])) { sm[0] = sm[w]; sa[0] = sa[w]; }
    }
    __syncthreads();
    float Mg = sm[0];

    float S = 0.f;
    for (int i = tid; i < NBLK; i += 256)
        S += ps[i] * __expf(pm[i] - Mg);
#pragma unroll
    for (int off = 1; off < 64; off <<= 1) S += __shfl_xor(S, off);
    if (lane == 0) ssum[wave] = S;
    __syncthreads();
    if (tid == 0) {
        float lz = Mg + logf(ssum[0] + ssum[1] + ssum[2] + ssum[3]);
        __hip_atomic_store(&logZ[r], lz, __ATOMIC_RELAXED, __HIP_MEMORY_SCOPE_AGENT);
        __hip_atomic_store(&pred[r], sa[0], __ATOMIC_RELAXED, __HIP_MEMORY_SCOPE_AGENT);
        __threadfence();                               // release
        unsigned int old = atomicAdd(counter, 1u);     // device-scope RMW
        lastflag = (old == 63u) ? 1 : 0;
    }
    __syncthreads();
    if (lastflag == 0) return;

    // ---- last block: scalar epilogue ----
    __threadfence();                                   // acquire
    __shared__ float lzs[64]; __shared__ int prs[64];
    if (tid < 64) {
        lzs[tid] = __hip_atomic_load(&logZ[tid], __ATOMIC_RELAXED, __HIP_MEMORY_SCOPE_AGENT);
        prs[tid] = __hip_atomic_load(&pred[tid], __ATOMIC_RELAXED, __HIP_MEMORY_SCOPE_AGENT);
    }
    __syncthreads();
    if (tid == 0) {
        float loop_loss[NLOOP], loop_acc[NLOOP], hasf[NLOOP];
        float n_has = 0.f, hms = 0.f, hcs = 0.f;
        for (int l = 0; l < NLOOP; ++l) {
            float cnt = 0.f, se = 0.f, sc = 0.f;
            for (int b = 0; b < BB; ++b) {
                int cl = chain_lens[b];
                int ti = l < cl - 1 ? l : cl - 1;
                int tgt = chain_targets[b * NLOOP + ti];
                int as = ans_starts[b];
                bool valid = (as >= 1) && (as < LLEN) && (tgt < VV);
                int idx = l * BB + b;
                float ce = lzs[idx] - tgt_logit[idx];
                float corr = (prs[idx] == tgt) ? 1.f : 0.f;
                if (valid) {
                    cnt += 1.f; se += ce; sc += corr;
                    if (tgt == HALT) { hms += 1.f; hcs += corr; }
                }
            }
            bool has = cnt > 0.f;
            hasf[l] = has ? 1.f : 0.f;
            n_has += hasf[l];
            float denom = cnt > 1.f ? cnt : 1.f;
            loop_loss[l] = has ? se / denom : 0.f;
            loop_acc[l]  = has ? sc / denom : 0.f;
        }
        float nn = n_has > 1.f ? n_has : 1.f;
        float avg_loss = 0.f, avg_acc = 0.f;
        for (int l = 0; l < NLOOP; ++l) {
            avg_loss += loop_loss[l] * hasf[l];
            avg_acc  += loop_acc[l]  * hasf[l];
        }
        avg_loss /= nn; avg_acc /= nn;
        int last_valid = NLOOP - 1;   // matches jnp.argmax on all-false reversed
        for (int l = NLOOP - 1; l >= 0; --l) if (hasf[l] > 0.f) { last_valid = l; break; }
        float ams = 0.f, aacc = 0.f;
        for (int l = 0; l < NLOOP; ++l) {
            float mask = (n_has > 1.f) ? (hasf[l] * ((l != last_valid) ? 1.f : 0.f)) : hasf[l];
            ams += mask; aacc += loop_acc[l] * mask;
        }
        float answer_acc = (ams > 0.f) ? (aacc / (ams > 1.f ? ams : 1.f)) : avg_acc;
        float halt_acc = (hms > 0.f) ? (hcs / (hms > 1.f ? hms : 1.f)) : 0.f;
        out[0] = avg_loss; out[1] = avg_acc; out[2] = answer_acc; out[3] = halt_acc;
    }
}

extern "C" void kernel_launch(void* const* d_in, const int* in_sizes, int n_in,
                              void* d_out, int out_size, void* d_ws, size_t ws_size,
                              hipStream_t stream) {
    const float* x   = (const float*)d_in[0];
    const float* res = (const float*)d_in[1];
    const float* nw  = (const float*)d_in[2];
    const float* W   = (const float*)d_in[3];
    const int* ans   = (const int*)d_in[4];
    const int* ct    = (const int*)d_in[5];
    const int* cl    = (const int*)d_in[6];
    float* out = (float*)d_out;

    char* ws = (char*)d_ws;
    unsigned short* hbf = (unsigned short*)ws;                       // 96 KiB
    float* tgtl = (float*)(ws + 98304);                              // 256 B
    size_t off = 98560;
    float* pmax = (float*)(ws + off);  off += (size_t)64 * NBLK * 4;
    float* psum = (float*)(ws + off);  off += (size_t)64 * NBLK * 4;
    int*   parg = (int*)  (ws + off);  off += (size_t)64 * NBLK * 4;
    float* logZ = (float*)(ws + off);  off += 256;
    int*   pred = (int*)  (ws + off);  off += 256;
    unsigned int* counter = (unsigned int*)(ws + off); off += 256;

    k_prep<<<64, 256, 0, stream>>>(x, res, nw, W, ans, ct, cl, hbf, tgtl, counter);
    k_logits<<<NBLK, 256, 0, stream>>>(W, hbf, pmax, psum, parg);
    k_combine<<<64, 256, 0, stream>>>(pmax, psum, parg, tgtl, ans, ct, cl,
                                      logZ, pred, counter, out);
}